// Round 4
// baseline (581.966 us; speedup 1.0000x reference)
//
#include <hip/hip_runtime.h>

// VanillaRNN: S=512, I=1, H=256, C=10, B=2048, fp32 in/out.
// R10: anti-phase dual-group structure. Model (R6-R9 post-mortems):
//  step = LDS(96*R) + trans(1024/R per SIMD) + MFMA(620/R) + exposed latency,
//  R = waves redundantly reading full h per 16-col group. R=8 (R6) is
//  LDS-bound (870) with +500 slop; R=4 plain (old R5) collapsed to 1712 via
//  1-wave/SIMD latency exposure; R7 proved duplicate-address reads don't cut
//  LDS cost; R9 proved intra-group pipelining can't hide 384-cyc bursts.
//  Fix: BN=32, 8 waves = TWO independent 16-col groups (G0=waves 0-3,
//  G1=waves 4-7; SIMD s hosts wave s + wave s+4 -> one of each). Two
//  barriers/step, groups in OPPOSITE phases:
//    interval A: G0 {read 8xb128 h_t, 32 MFMA}   G1 {tanh, write h_t}
//    interval B: G0 {tanh, write h_{t+1}}        G1 {read h_t, 32 MFMA}
//  Per interval: LDS 384+96=480; trans 256 and MFMA 155 hide under it on the
//  paired wave's complementary pipes. Single h-buffer per group (barriers
//  separate each group's read/write phases). 64 blocks (chain is sequential;
//  block count only affects clocks).
// Kept: XOR swizzle sw=(n&7)^((n>>3)<<2); x folded into MFMA C; x prefetch;
// weights pre-scaled by 2*log2e: tanh = 1 - 2*rcp(exp2(s)+1).

#define SEQ    512
#define HID    256
#define NCLS   10
#define BN     32     // 2 groups x 16 cols
#define NT     512    // 8 waves
#define XP     33     // xs row pitch

typedef _Float16 f16x8 __attribute__((ext_vector_type(8)));
typedef _Float16 f16x4 __attribute__((ext_vector_type(4)));
typedef float    f32x4 __attribute__((ext_vector_type(4)));

#define MFMA16(a, b, c) __builtin_amdgcn_mfma_f32_16x16x32_f16(a, b, c, 0, 0, 0)

__global__ __launch_bounds__(NT)
__attribute__((amdgpu_waves_per_eu(2, 2)))
void rnn_mfma(
    const float* __restrict__ x,     // [B, S]
    const float* __restrict__ W_hx,  // [H]
    const float* __restrict__ W_hh,  // [H, H]
    const float* __restrict__ W_ph,  // [C, H]
    const float* __restrict__ b_h,   // [H]
    const float* __restrict__ b_p,   // [C]
    float* __restrict__ out)         // [B, C]
{
    // hT[g][n][j]: h row j, col n of group g; chunk c (8 f16) at c ^ sw(n)
    __shared__ __align__(16) _Float16 hT[2][16][HID];   // 16 KB
    __shared__ __align__(16) float xs[SEQ + 2][XP];     // 67.8 KB

    const int tid  = threadIdx.x;
    const int lane = tid & 63;
    const int wave = tid >> 6;       // 0..7
    const int g    = wave >> 2;      // group 0/1
    const int w4   = wave & 3;       // row-split index within group
    const int n16  = lane & 15;
    const int quad = lane >> 4;      // 0..3
    const int sw   = (n16 & 7) ^ ((n16 >> 3) << 2);
    const int col  = g * 16 + n16;   // batch col within block
    const int b0   = blockIdx.x * BN;

    const float SC = 2.885390081777926814f;   // 2*log2(e)

    // ---- A-frags: 4 m-tiles, rows w4*64 + i*16 + n16, scaled, f16 ----
    f16x8 afrag[4][8];
#pragma unroll
    for (int i = 0; i < 4; ++i) {
        const int row = w4 * 64 + i * 16 + n16;
#pragma unroll
        for (int ks = 0; ks < 8; ++ks) {
            const float4* p = (const float4*)&W_hh[row * HID + ks * 32 + quad * 8];
            float4 u = p[0], v = p[1];
            f16x8 a;
            a[0] = (_Float16)(SC * u.x); a[1] = (_Float16)(SC * u.y);
            a[2] = (_Float16)(SC * u.z); a[3] = (_Float16)(SC * u.w);
            a[4] = (_Float16)(SC * v.x); a[5] = (_Float16)(SC * v.y);
            a[6] = (_Float16)(SC * v.z); a[7] = (_Float16)(SC * v.w);
            afrag[i][ks] = a;
        }
    }
    // D rows for this lane: row = w4*64 + i*16 + quad*4 + r
    f32x4 bias[4], wxv[4];
#pragma unroll
    for (int i = 0; i < 4; ++i)
#pragma unroll
        for (int r = 0; r < 4; ++r) {
            const int row = w4 * 64 + i * 16 + quad * 4 + r;
            bias[i][r] = SC * b_h[row];
            wxv[i][r]  = SC * W_hx[row];
        }

    // ---- swizzled byte offsets within this group's buffer ----
    const char* hb = (const char*)hT[g];
    int roff[8], woff[4];
#pragma unroll
    for (int ks = 0; ks < 8; ++ks)
        roff[ks] = (n16 * HID + (((4 * ks + quad) ^ sw) << 3)) * 2;
#pragma unroll
    for (int i = 0; i < 4; ++i)
        woff[i] = (n16 * HID +
                   (((2 * (w4 * 4 + i) + (quad >> 1)) ^ sw) << 3) +
                   (quad & 1) * 4) * 2;

    // ---- stage xs[t][n] = x[b0+n][t] ----
    for (int i = tid; i < BN * SEQ / 4; i += NT) {
        const int n = i >> 7, t4 = (i & 127) * 4;
        float4 v = *(const float4*)&x[(b0 + n) * SEQ + t4];
        xs[t4 + 0][n] = v.x; xs[t4 + 1][n] = v.y;
        xs[t4 + 2][n] = v.z; xs[t4 + 3][n] = v.w;
    }
    // ---- h0 = 0 (both groups) ----
    for (int i = tid; i < 2 * 16 * HID / 2; i += NT) ((float*)hT)[i] = 0.0f;
    __syncthreads();

    float xv = xs[0][col];
    f32x4 acc[4];

#define READ_MFMA(T)                                                          \
    {                                                                         \
        const float xnxt = xs[(T) + 1][col];                                  \
        f16x8 bfr[8];                                                         \
        _Pragma("unroll")                                                     \
        for (int ks = 0; ks < 8; ++ks)                                        \
            bfr[ks] = *(const f16x8*)(hb + roff[ks]);                         \
        _Pragma("unroll")                                                     \
        for (int i = 0; i < 4; ++i) {                                         \
            f32x4 c0;                                                         \
            _Pragma("unroll")                                                 \
            for (int r = 0; r < 4; ++r)                                       \
                c0[r] = fmaf(wxv[i][r], xv, bias[i][r]);                      \
            acc[i] = MFMA16(afrag[i][0], bfr[0], c0);                         \
        }                                                                     \
        _Pragma("unroll")                                                     \
        for (int ks = 1; ks < 8; ++ks)                                        \
            _Pragma("unroll")                                                 \
            for (int i = 0; i < 4; ++i)                                       \
                acc[i] = MFMA16(afrag[i][ks], bfr[ks], acc[i]);               \
        xv = xnxt;                                                            \
    }

#define TANH_WRITE()                                                          \
    {                                                                         \
        _Pragma("unroll")                                                     \
        for (int i = 0; i < 4; ++i) {                                         \
            f16x4 h4;                                                         \
            _Pragma("unroll")                                                 \
            for (int r = 0; r < 4; ++r) {                                     \
                float ex = __builtin_amdgcn_exp2f(acc[i][r]);                 \
                float rc = __builtin_amdgcn_rcpf(ex + 1.0f);                  \
                h4[r] = (_Float16)(1.0f - 2.0f * rc);                         \
            }                                                                 \
            *(f16x4*)((char*)hb + woff[i]) = h4;                              \
        }                                                                     \
    }

    for (int t = 0; t < SEQ; ++t) {
        // interval A: G0 reads h_t + MFMAs; G1 finishes h_t (tanh+write)
        if (g == 0) {
            READ_MFMA(t)
        } else if (t > 0) {
            TANH_WRITE()
        }
        __syncthreads();
        // interval B: G0 finishes h_{t+1}; G1 reads h_t + MFMAs
        if (g == 0) {
            TANH_WRITE()
        } else {
            READ_MFMA(t)
        }
        __syncthreads();
    }
    // tail: G1's h_512
    if (g == 1) { TANH_WRITE() }
    __syncthreads();

#undef READ_MFMA
#undef TANH_WRITE

    // ---- output: out[b][c] = b_p[c] + sum_j W_ph[c][j] * h_final[j][b] ----
    // final h of col b in hT[b>>4][b&15]; element j at chunk (j>>3)^sw(b&15)
    if (tid < BN * NCLS) {
        const int b = tid / NCLS, c = tid % NCLS;
        const int bc = b & 15;
        const int sb = (bc & 7) ^ ((bc >> 3) << 2);
        float sum = b_p[c];
        const _Float16* hp = hT[b >> 4][bc];
        for (int j = 0; j < HID; ++j) {
            const int ph = ((((j >> 3) ^ sb) << 3) | (j & 7));
            sum += W_ph[c * HID + j] * (float)hp[ph];
        }
        out[(b0 + b) * NCLS + c] = sum;
    }
}

extern "C" void kernel_launch(void* const* d_in, const int* in_sizes, int n_in,
                              void* d_out, int out_size, void* d_ws, size_t ws_size,
                              hipStream_t stream) {
    const float* x    = (const float*)d_in[0];
    const float* W_hx = (const float*)d_in[1];
    const float* W_hh = (const float*)d_in[2];
    const float* W_ph = (const float*)d_in[3];
    const float* b_h  = (const float*)d_in[4];
    const float* b_p  = (const float*)d_in[5];
    float* out = (float*)d_out;

    rnn_mfma<<<dim3(2048 / BN), dim3(NT), 0, stream>>>(
        x, W_hx, W_hh, W_ph, b_h, b_p, out);
}

// Round 5
// 556.277 us; speedup vs baseline: 1.0462x; 1.0462x over previous
//
#include <hip/hip_runtime.h>

// VanillaRNN: S=512, I=1, H=256, C=10, B=2048, fp32 in/out.
// R11: dual column-group ILP. R10 post-mortem: R=4 (64 rows/wave) needs 128
// VGPRs of afrag -> spill catastrophe (WRITE_SIZE 80KB->7.2MB). R6 analysis:
// reads are already bank-optimal; step = LDS(560-850) + ~500 fixed serial
// (read-latency head, MFMA chain, tanh/write/barrier tail). Block count and
// BN don't change per-col LDS traffic (invariant R x 8KB per 16 cols).
// => Only remaining lever: amortize the ~500 fixed cost over 2x work.
// BN=32: each wave keeps R6's exact shape (32 rows, afrag=64 regs) but runs
// TWO independent 16-col groups per step. G1's reads issue under G0's MFMA
// chain (independent; compiler interleaves via partial lgkmcnt), G1's MFMAs
// under G0's tanh. One barrier/step. G1 addressed via +8192B immediate
// offsets (no extra addr regs). ~190 VGPRs total -> no spill at 2 waves/SIMD.
// 64 blocks x 8 waves. Kept: XOR swizzle sw=(n&7)^((n>>3)<<2) (bank-even),
// x folded into MFMA C, x prefetch, weights pre-scaled by 2*log2e:
// tanh = 1 - 2*rcp(exp2(s)+1).

#define SEQ    512
#define HID    256
#define NCLS   10
#define BN     32     // 2 groups x 16 cols
#define NT     512    // 8 waves
#define XP     33     // xs row pitch (odd -> bank spread)
#define G1OFF  8192   // byte offset of group 1 in hT buffer (16*HID*2)

typedef _Float16 f16x8 __attribute__((ext_vector_type(8)));
typedef _Float16 f16x4 __attribute__((ext_vector_type(4)));
typedef float    f32x4 __attribute__((ext_vector_type(4)));

#define MFMA16(a, b, c) __builtin_amdgcn_mfma_f32_16x16x32_f16(a, b, c, 0, 0, 0)

__global__ __launch_bounds__(NT)
__attribute__((amdgpu_waves_per_eu(2, 2)))
void rnn_mfma(
    const float* __restrict__ x,     // [B, S]
    const float* __restrict__ W_hx,  // [H]
    const float* __restrict__ W_hh,  // [H, H]
    const float* __restrict__ W_ph,  // [C, H]
    const float* __restrict__ b_h,   // [H]
    const float* __restrict__ b_p,   // [C]
    float* __restrict__ out)         // [B, C]
{
    // hT[buf][n][j]: h row j, col n; chunk c (8 f16) at c ^ sw(n&15)
    __shared__ __align__(16) _Float16 hT[2][BN][HID];   // 32 KB
    __shared__ __align__(16) float xs[SEQ + 2][XP];     // 67.8 KB

    const int tid  = threadIdx.x;
    const int lane = tid & 63;
    const int wave = tid >> 6;       // 0..7
    const int n16  = lane & 15;
    const int quad = lane >> 4;      // 0..3
    const int sw   = (n16 & 7) ^ ((n16 >> 3) << 2);
    const int b0   = blockIdx.x * BN;

    const float SC = 2.885390081777926814f;   // 2*log2(e)

    // ---- A-frags: rows wave*32 + mt*16 + n16, pre-scaled by SC, f16 ----
    f16x8 afrag[2][8];
#pragma unroll
    for (int mt = 0; mt < 2; ++mt) {
        const int row = wave * 32 + mt * 16 + n16;
#pragma unroll
        for (int ks = 0; ks < 8; ++ks) {
            const float4* p = (const float4*)&W_hh[row * HID + ks * 32 + quad * 8];
            float4 u = p[0], v = p[1];
            f16x8 a;
            a[0] = (_Float16)(SC * u.x); a[1] = (_Float16)(SC * u.y);
            a[2] = (_Float16)(SC * u.z); a[3] = (_Float16)(SC * u.w);
            a[4] = (_Float16)(SC * v.x); a[5] = (_Float16)(SC * v.y);
            a[6] = (_Float16)(SC * v.z); a[7] = (_Float16)(SC * v.w);
            afrag[mt][ks] = a;
        }
    }
    // D rows for this lane: row = wave*32 + mt*16 + quad*4 + r
    f32x4 bias[2], wxv[2];
#pragma unroll
    for (int mt = 0; mt < 2; ++mt)
#pragma unroll
        for (int r = 0; r < 4; ++r) {
            const int row = wave * 32 + mt * 16 + quad * 4 + r;
            bias[mt][r] = SC * b_h[row];
            wxv[mt][r]  = SC * W_hx[row];
        }

    // ---- swizzled byte offsets (group 0; group 1 = +G1OFF immediate) ----
    int roff[8], woff[2];
#pragma unroll
    for (int ks = 0; ks < 8; ++ks)
        roff[ks] = (n16 * HID + (((4 * ks + quad) ^ sw) << 3)) * 2;
#pragma unroll
    for (int mt = 0; mt < 2; ++mt)
        woff[mt] = (n16 * HID +
                    (((4 * wave + 2 * mt + (quad >> 1)) ^ sw) << 3) +
                    (quad & 1) * 4) * 2;

    // ---- stage xs[t][n] = x[b0+n][t] ----
    for (int i = tid; i < BN * SEQ / 4; i += NT) {
        const int n = i >> 7, t4 = (i & 127) * 4;
        float4 v = *(const float4*)&x[(b0 + n) * SEQ + t4];
        xs[t4 + 0][n] = v.x; xs[t4 + 1][n] = v.y;
        xs[t4 + 2][n] = v.z; xs[t4 + 3][n] = v.w;
    }
    // ---- h0 = 0 (buffer 0 only; buffer 1 fully written each odd step) ----
    for (int i = tid; i < BN * HID / 2; i += NT) ((float*)hT[0])[i] = 0.0f;
    __syncthreads();

    float xv0 = xs[0][n16];         // group-0 x, prefetched
    float xv1 = xs[0][16 + n16];    // group-1 x

#define TANH_W(ACC, MT, GOFF)                                                 \
    {                                                                         \
        f16x4 h4;                                                             \
        _Pragma("unroll")                                                     \
        for (int r = 0; r < 4; ++r) {                                         \
            float ex = __builtin_amdgcn_exp2f(ACC[r]);                        \
            float rc = __builtin_amdgcn_rcpf(ex + 1.0f);                      \
            h4[r] = (_Float16)(1.0f - 2.0f * rc);                             \
        }                                                                     \
        *(f16x4*)(wb + woff[MT] + (GOFF)) = h4;                               \
    }

#define RNN_STEP(T, RD, WR)                                                   \
    {                                                                         \
        const float xn0 = xs[(T) + 1][n16];                                   \
        const float xn1 = xs[(T) + 1][16 + n16];                              \
        const char* rb = (const char*)hT[RD];                                 \
        char*       wb = (char*)hT[WR];                                       \
        f16x8 bfr0[8], bfr1[8];                                               \
        _Pragma("unroll")                                                     \
        for (int ks = 0; ks < 8; ++ks)                                        \
            bfr0[ks] = *(const f16x8*)(rb + roff[ks]);                        \
        _Pragma("unroll")                                                     \
        for (int ks = 0; ks < 8; ++ks)                                        \
            bfr1[ks] = *(const f16x8*)(rb + roff[ks] + G1OFF);                \
        f32x4 a0[2], a1[2];                                                   \
        _Pragma("unroll")                                                     \
        for (int mt = 0; mt < 2; ++mt) {                                      \
            f32x4 c0;                                                         \
            _Pragma("unroll")                                                 \
            for (int r = 0; r < 4; ++r)                                       \
                c0[r] = fmaf(wxv[mt][r], xv0, bias[mt][r]);                   \
            a0[mt] = MFMA16(afrag[mt][0], bfr0[0], c0);                       \
        }                                                                     \
        _Pragma("unroll")                                                     \
        for (int ks = 1; ks < 8; ++ks)                                        \
            _Pragma("unroll")                                                 \
            for (int mt = 0; mt < 2; ++mt)                                    \
                a0[mt] = MFMA16(afrag[mt][ks], bfr0[ks], a0[mt]);             \
        _Pragma("unroll")                                                     \
        for (int mt = 0; mt < 2; ++mt) {                                      \
            f32x4 c1;                                                         \
            _Pragma("unroll")                                                 \
            for (int r = 0; r < 4; ++r)                                       \
                c1[r] = fmaf(wxv[mt][r], xv1, bias[mt][r]);                   \
            a1[mt] = MFMA16(afrag[mt][0], bfr1[0], c1);                       \
        }                                                                     \
        TANH_W(a0[0], 0, 0)                                                   \
        TANH_W(a0[1], 1, 0)                                                   \
        _Pragma("unroll")                                                     \
        for (int ks = 1; ks < 8; ++ks)                                        \
            _Pragma("unroll")                                                 \
            for (int mt = 0; mt < 2; ++mt)                                    \
                a1[mt] = MFMA16(afrag[mt][ks], bfr1[ks], a1[mt]);             \
        TANH_W(a1[0], 0, G1OFF)                                               \
        TANH_W(a1[1], 1, G1OFF)                                               \
        xv0 = xn0; xv1 = xn1;                                                 \
        __syncthreads();                                                      \
    }

    for (int t = 0; t < SEQ; t += 2) {
        RNN_STEP(t, 0, 1);
        RNN_STEP(t + 1, 1, 0);
    }
#undef RNN_STEP
#undef TANH_W

    // ---- output: out[b][c] = b_p[c] + sum_j W_ph[c][j] * h_final[j][b] ----
    // final h in hT[0]; element (n=b, k=j) at chunk (j>>3) ^ sw(b&15)
    if (tid < BN * NCLS) {
        const int b = tid / NCLS, c = tid % NCLS;
        const int sb = (b & 7) ^ (((b >> 3) & 1) << 2);
        float sum = b_p[c];
        const _Float16* hp = hT[0][b];
        for (int j = 0; j < HID; ++j) {
            const int ph = ((((j >> 3) ^ sb) << 3) | (j & 7));
            sum += W_ph[c * HID + j] * (float)hp[ph];
        }
        out[(b0 + b) * NCLS + c] = sum;
    }
}

extern "C" void kernel_launch(void* const* d_in, const int* in_sizes, int n_in,
                              void* d_out, int out_size, void* d_ws, size_t ws_size,
                              hipStream_t stream) {
    const float* x    = (const float*)d_in[0];
    const float* W_hx = (const float*)d_in[1];
    const float* W_hh = (const float*)d_in[2];
    const float* W_ph = (const float*)d_in[3];
    const float* b_h  = (const float*)d_in[4];
    const float* b_p  = (const float*)d_in[5];
    float* out = (float*)d_out;

    rnn_mfma<<<dim3(2048 / BN), dim3(NT), 0, stream>>>(
        x, W_hx, W_hh, W_ph, b_h, b_p, out);
}

// Round 6
// 332.371 us; speedup vs baseline: 1.7510x; 1.6737x over previous
//
#include <hip/hip_runtime.h>

// VanillaRNN: S=512, I=1, H=256, C=10, B=2048, fp32 in/out.
// R12: R6 base (only structure that performs: BN=16, 8 waves, 128 blocks,
// 32 rows/wave, 1 barrier/step, 291us) + two surgical changes:
//  (1) hT pitch 264 f16 (528B = 33 chunks), LINEAR chunk layout, no XOR:
//      bank group of read (n16+4ks+quad)&7 -> exactly 8 lanes per 4-bank
//      group per ds_read_b128 (even, same as swizzle), writes also even;
//      AND roff stride is lane-invariant 64B -> single base reg +
//      compile-time offset: immediates (kills ~10 addr-VALU/step/wave,
//      which R6 paid because XOR deltas were lane-dependent).
//  (2) parity-staggered K-order: waves w and w+4 share a SIMD (wave>>2
//      parity); they process K-halves in opposite order (0-3,4-7 vs
//      4-7,0-3). R6's two co-resident waves sat in identical phases
//      (read together, MFMA together, tanh together -> serialized pipes);
//      stagger anti-aligns their LDS bursts and MFMA blocks. f32 accum
//      order change only.
// R11 post-mortem: dual-group ILP serialized (VGPR_Count=88 == R6 proves
// compiler reused regs, no overlap); grid/BN NEVER helps (time = 512 x
// per-block step). SQ_LDS_BANK_CONFLICT ~5/read across 3 swizzles =
// multi-pass artifact, non-diagnostic.
// Kept: x folded into MFMA C-operand, x prefetch 1 step ahead, weights
// pre-scaled by 2*log2e: tanh = 1 - 2*rcp(exp2(s)+1).

#define SEQ    512
#define HID    256
#define NCLS   10
#define BN     16     // batch per block
#define NT     512    // 8 waves
#define XP     17     // xs row pitch
#define PITCH  264    // f16 per column (528 B = 33 x 16B chunks, coprime 8)

typedef _Float16 f16x8 __attribute__((ext_vector_type(8)));
typedef _Float16 f16x4 __attribute__((ext_vector_type(4)));
typedef float    f32x4 __attribute__((ext_vector_type(4)));

#define MFMA16(a, b, c) __builtin_amdgcn_mfma_f32_16x16x32_f16(a, b, c, 0, 0, 0)

__global__ __launch_bounds__(NT)
__attribute__((amdgpu_waves_per_eu(2, 2)))
void rnn_mfma(
    const float* __restrict__ x,     // [B, S]
    const float* __restrict__ W_hx,  // [H]
    const float* __restrict__ W_hh,  // [H, H]
    const float* __restrict__ W_ph,  // [C, H]
    const float* __restrict__ b_h,   // [H]
    const float* __restrict__ b_p,   // [C]
    float* __restrict__ out)         // [B, C]
{
    // hT[buf][n][j]: h element (row j, col n) at f16 index j (LINEAR),
    // row pitch 264 f16 -> bank-even for both reads and writes.
    __shared__ __align__(16) _Float16 hT[2][BN][PITCH];   // 16.5 KB
    __shared__ __align__(16) float xs[SEQ + 2][XP];       // 34.9 KB

    const int tid  = threadIdx.x;
    const int lane = tid & 63;
    const int wave = tid >> 6;       // 0..7
    const int n16  = lane & 15;
    const int quad = lane >> 4;      // 0..3
    const int b0   = blockIdx.x * BN;

    const float SC = 2.885390081777926814f;   // 2*log2(e)

    // ---- A-frags: rows wave*32 + mt*16 + n16, pre-scaled by SC, f16 ----
    // A[m = n16][k = quad*8 + j]
    f16x8 afrag[2][8];
#pragma unroll
    for (int mt = 0; mt < 2; ++mt) {
        const int row = wave * 32 + mt * 16 + n16;
#pragma unroll
        for (int ks = 0; ks < 8; ++ks) {
            const float4* p = (const float4*)&W_hh[row * HID + ks * 32 + quad * 8];
            float4 u = p[0], v = p[1];
            f16x8 a;
            a[0] = (_Float16)(SC * u.x); a[1] = (_Float16)(SC * u.y);
            a[2] = (_Float16)(SC * u.z); a[3] = (_Float16)(SC * u.w);
            a[4] = (_Float16)(SC * v.x); a[5] = (_Float16)(SC * v.y);
            a[6] = (_Float16)(SC * v.z); a[7] = (_Float16)(SC * v.w);
            afrag[mt][ks] = a;
        }
    }
    // D rows for this lane: row = wave*32 + mt*16 + quad*4 + r
    f32x4 bias[2], wxv[2];
#pragma unroll
    for (int mt = 0; mt < 2; ++mt)
#pragma unroll
        for (int r = 0; r < 4; ++r) {
            const int row = wave * 32 + mt * 16 + quad * 4 + r;
            bias[mt][r] = SC * b_h[row];
            wxv[mt][r]  = SC * W_hx[row];
        }

    // ---- linear byte bases (per lane), immediates do the rest ----
    // read:  col n16, rows ks*32 + quad*8 + j  -> rbase + ks*64
    // write: col n16, rows wave*32 + mt*16 + quad*4 + r -> wbase + mt*32
    const int rbase = n16 * (PITCH * 2) + quad * 16;
    const int wbase = n16 * (PITCH * 2) + wave * 64 + quad * 8;

    // ---- stage xs[t][n] = x[b0+n][t] ----
    for (int i = tid; i < BN * SEQ / 4; i += NT) {
        const int n = i >> 7, t4 = (i & 127) * 4;
        float4 v = *(const float4*)&x[(b0 + n) * SEQ + t4];
        xs[t4 + 0][n] = v.x; xs[t4 + 1][n] = v.y;
        xs[t4 + 2][n] = v.z; xs[t4 + 3][n] = v.w;
    }
    // ---- h0 = 0 (buffer 0 only; buffer 1 fully written each odd step) ----
    for (int i = tid; i < BN * PITCH / 2; i += NT) ((float*)hT[0])[i] = 0.0f;
    __syncthreads();

    float xv = xs[0][n16];   // prefetched x_t for step 0

#define RNN_STEP(T, RD, WR, P)                                                \
    {                                                                         \
        const float xnxt = xs[(T) + 1][n16];  /* prefetch next step's x */    \
        const char* rb = (const char*)hT[RD] + rbase;                         \
        char*       wb = (char*)hT[WR] + wbase;                               \
        /* burst 1: K-chunks P..P+3 */                                        \
        f16x8 bA0 = *(const f16x8*)(rb + (((P) + 0) & 7) * 64);               \
        f16x8 bA1 = *(const f16x8*)(rb + (((P) + 1) & 7) * 64);               \
        f16x8 bA2 = *(const f16x8*)(rb + (((P) + 2) & 7) * 64);               \
        f16x8 bA3 = *(const f16x8*)(rb + (((P) + 3) & 7) * 64);               \
        f32x4 acc[2];                                                         \
        _Pragma("unroll")                                                     \
        for (int mt = 0; mt < 2; ++mt) {                                      \
            f32x4 c0;                                                         \
            _Pragma("unroll")                                                 \
            for (int r = 0; r < 4; ++r)                                       \
                c0[r] = fmaf(wxv[mt][r], xv, bias[mt][r]);                    \
            acc[mt] = MFMA16(afrag[mt][((P) + 0) & 7], bA0, c0);              \
        }                                                                     \
        acc[0] = MFMA16(afrag[0][((P) + 1) & 7], bA1, acc[0]);                \
        acc[1] = MFMA16(afrag[1][((P) + 1) & 7], bA1, acc[1]);                \
        /* burst 2 issues under burst-1 MFMAs */                              \
        f16x8 bB0 = *(const f16x8*)(rb + (((P) + 4) & 7) * 64);               \
        f16x8 bB1 = *(const f16x8*)(rb + (((P) + 5) & 7) * 64);               \
        f16x8 bB2 = *(const f16x8*)(rb + (((P) + 6) & 7) * 64);               \
        f16x8 bB3 = *(const f16x8*)(rb + (((P) + 7) & 7) * 64);               \
        acc[0] = MFMA16(afrag[0][((P) + 2) & 7], bA2, acc[0]);                \
        acc[1] = MFMA16(afrag[1][((P) + 2) & 7], bA2, acc[1]);                \
        acc[0] = MFMA16(afrag[0][((P) + 3) & 7], bA3, acc[0]);                \
        acc[1] = MFMA16(afrag[1][((P) + 3) & 7], bA3, acc[1]);                \
        acc[0] = MFMA16(afrag[0][((P) + 4) & 7], bB0, acc[0]);                \
        acc[1] = MFMA16(afrag[1][((P) + 4) & 7], bB0, acc[1]);                \
        acc[0] = MFMA16(afrag[0][((P) + 5) & 7], bB1, acc[0]);                \
        acc[1] = MFMA16(afrag[1][((P) + 5) & 7], bB1, acc[1]);                \
        acc[0] = MFMA16(afrag[0][((P) + 6) & 7], bB2, acc[0]);                \
        acc[1] = MFMA16(afrag[1][((P) + 6) & 7], bB2, acc[1]);                \
        acc[0] = MFMA16(afrag[0][((P) + 7) & 7], bB3, acc[0]);                \
        acc[1] = MFMA16(afrag[1][((P) + 7) & 7], bB3, acc[1]);                \
        _Pragma("unroll")                                                     \
        for (int mt = 0; mt < 2; ++mt) {                                      \
            f16x4 h4;                                                         \
            _Pragma("unroll")                                                 \
            for (int r = 0; r < 4; ++r) {                                     \
                float ex = __builtin_amdgcn_exp2f(acc[mt][r]);                \
                float rc = __builtin_amdgcn_rcpf(ex + 1.0f);                  \
                h4[r] = (_Float16)(1.0f - 2.0f * rc);                         \
            }                                                                 \
            *(f16x4*)(wb + mt * 32) = h4;                                     \
        }                                                                     \
        xv = xnxt;                                                            \
        __syncthreads();                                                      \
    }

    // parity = wave>>2: waves w and w+4 share a SIMD -> opposite K-order
    if (((wave >> 2) & 1) == 0) {
        for (int t = 0; t < SEQ; t += 2) {
            RNN_STEP(t,     0, 1, 0)
            RNN_STEP(t + 1, 1, 0, 0)
        }
    } else {
        for (int t = 0; t < SEQ; t += 2) {
            RNN_STEP(t,     0, 1, 4)
            RNN_STEP(t + 1, 1, 0, 4)
        }
    }
#undef RNN_STEP

    // ---- output: out[b][c] = b_p[c] + sum_j W_ph[c][j] * h_final[j][b] ----
    // final h in hT[0]; LINEAR: element (col b, row j) at hT[0][b][j]
    if (tid < BN * NCLS) {
        const int b = tid / NCLS, c = tid % NCLS;
        float sum = b_p[c];
        const _Float16* hp = hT[0][b];
        for (int j = 0; j < HID; ++j)
            sum += W_ph[c * HID + j] * (float)hp[j];
        out[(b0 + b) * NCLS + c] = sum;
    }
}

extern "C" void kernel_launch(void* const* d_in, const int* in_sizes, int n_in,
                              void* d_out, int out_size, void* d_ws, size_t ws_size,
                              hipStream_t stream) {
    const float* x    = (const float*)d_in[0];
    const float* W_hx = (const float*)d_in[1];
    const float* W_hh = (const float*)d_in[2];
    const float* W_ph = (const float*)d_in[3];
    const float* b_h  = (const float*)d_in[4];
    const float* b_p  = (const float*)d_in[5];
    float* out = (float*)d_out;

    rnn_mfma<<<dim3(2048 / BN), dim3(NT), 0, stream>>>(
        x, W_hx, W_hh, W_ph, b_h, b_p, out);
}